// Round 5
// baseline (157.462 us; speedup 1.0000x reference)
//
#include <hip/hip_runtime.h>
#include <math.h>

#define B_ROWS 8192
#define NPROTO 10
#define NCLS   10
#define NPATCH 196

// workspace layout (floats)
#define TABLE_OFF 0                          // 80: per proto [cy0..3, sy0..3]
#define WT2_OFF   128                        // 19600: [p][proto][c]
#define PART_OFF  19776                      // 7*8192*10 partial logits
#define PART_ELEMS (7 * B_ROWS * NCLS)
#define CNT_OFF   (PART_OFF + PART_ELEMS)    // 128 ints (group done-counters)
#define XS_STRIDE 113                        // 113%32=17, gcd(17,32)=1 -> conflict-free

typedef float v2f __attribute__((ext_vector_type(2)));

// ---------- prep: sincos table + weight transpose + zero group counters ----------
__global__ __launch_bounds__(256) void quanv_prep(
    const float* __restrict__ W, const float* __restrict__ protos,
    float* __restrict__ ws) {
  int idx = blockIdx.x * 256 + threadIdx.x;
  if (idx < NPROTO * 8) {
    int proto = idx >> 3;
    int j = idx & 7;
    float h = 0.5f * protos[proto * 4 + (j & 3)];
    ws[TABLE_OFF + idx] = (j < 4) ? __cosf(h) : __sinf(h);
  }
  if (idx < 128) ((int*)(ws + CNT_OFF))[idx] = 0;
  if (idx < NPATCH * NPROTO * NCLS) {
    int p     = idx / (NPROTO * NCLS);
    int rem   = idx - p * (NPROTO * NCLS);
    int proto = rem / NCLS;
    int c     = rem - proto * NCLS;
    ws[WT2_OFF + idx] = W[c * (NPROTO * NPATCH) + proto * NPATCH + p];
  }
}

// ---------- main: LDS-staged x, scalar weights, fused last-block softmax ----------
__global__ __launch_bounds__(256, 4) void quanv_main(
    const float* __restrict__ x, const float* __restrict__ ws,
    float* __restrict__ partial, int* __restrict__ cnt,
    const float* __restrict__ bias, float* __restrict__ out) {
  __shared__ float xs[64 * XS_STRIDE];      // 28.3 KB; reused as reduction buffer
  __shared__ int amLast;

  const int tid = threadIdx.x;
  const int bx  = blockIdx.x;               // row group (64 rows)
  const int pr2 = blockIdx.y;               // pair of patch-rows, 0..6

  // Stage 64 rows x 112 floats (image rows 4*pr2..4*pr2+3), coalesced float4.
  {
    const float* src = x + (size_t)bx * 64 * 784 + pr2 * 112;
    for (int i = tid; i < 64 * 28; i += 256) {
      int row = i / 28, quad = i - row * 28;
      float4 v = *(const float4*)(src + (size_t)row * 784 + quad * 4);
      float* d = &xs[row * XS_STRIDE + quad * 4];
      d[0] = v.x; d[1] = v.y; d[2] = v.z; d[3] = v.w;
    }
  }
  __syncthreads();

  const int wid  = __builtin_amdgcn_readfirstlane(tid >> 6);
  const int lane = tid & 63;                // lane = row within group
  const float* tb  = ws + TABLE_OFF;
  const float* Wt2 = ws + WT2_OFF;
  const float* xr  = &xs[lane * XS_STRIDE];

  v2f acc2[5];
#pragma unroll
  for (int k = 0; k < 5; ++k) acc2[k] = (v2f){0.0f, 0.0f};

  for (int j = 0; j < 7; ++j) {             // 28 patches / 4 waves = 7 each
    int lp  = wid * 7 + j;                  // local patch 0..27 (uniform)
    int piL = lp >= 14 ? 1 : 0;
    int pj  = lp - piL * 14;
    int off = piL * 56 + 2 * pj;
    float x0 = xr[off],      x1 = xr[off + 1];
    float x2 = xr[off + 28], x3 = xr[off + 29];
    float s0, c0, s1, c1, s2, c2, s3, c3;
    __sincosf(0.5f * x0, &s0, &c0);
    __sincosf(0.5f * x1, &s1, &c1);
    __sincosf(0.5f * x2, &s2, &c2);
    __sincosf(0.5f * x3, &s3, &c3);
    v2f cv01 = {c0, c1}, cv23 = {c2, c3};
    v2f sv01 = {s0, s1}, sv23 = {s2, s3};

    int p = pr2 * 28 + lp;                  // global patch (uniform)
    const float* wp = Wt2 + p * (NPROTO * NCLS);
#pragma unroll
    for (int proto = 0; proto < NPROTO; ++proto) {
      const float* t8 = tb + proto * 8;     // uniform -> s_load
      v2f tc01 = {t8[0], t8[1]}, tc23 = {t8[2], t8[3]};
      v2f ts01 = {t8[4], t8[5]}, ts23 = {t8[6], t8[7]};
      v2f t01 = __builtin_elementwise_fma(cv01, tc01, sv01 * ts01);
      v2f t23 = __builtin_elementwise_fma(cv23, tc23, sv23 * ts23);
      float q  = fabsf((t01.x * t01.y) * (t23.x * t23.y));
      v2f qq = {q, q};
      const v2f* wv = (const v2f*)(wp + proto * NCLS);  // uniform -> s_load
#pragma unroll
      for (int k = 0; k < 5; ++k)
        acc2[k] = __builtin_elementwise_fma(qq, wv[k], acc2[k]);
    }
  }

  // cross-wave reduction: reuse xs (dead) as red buffer, stride 11
  __syncthreads();
  {
    float* myred = &xs[(wid * 64 + lane) * 11];
#pragma unroll
    for (int k = 0; k < 5; ++k) {
      myred[2 * k]     = acc2[k].x;
      myred[2 * k + 1] = acc2[k].y;
    }
  }
  __syncthreads();

  for (int i = tid; i < 64 * NCLS; i += 256) {
    int row = i / NCLS, c = i - row * NCLS;
    int o = row * 11 + c;
    float s = xs[o] + xs[704 + o] + xs[1408 + o] + xs[2112 + o];
    partial[((size_t)pr2 * B_ROWS + (size_t)bx * 64 + row) * NCLS + c] = s;
  }

  // ---- last-block-done: fused bias + log_softmax (order-independent) ----
  __threadfence();                          // release: partials device-visible
  __syncthreads();                          // all threads' fences done
  if (tid == 0) amLast = (atomicAdd(&cnt[bx], 1) == 6);  // device-scope RMW
  __syncthreads();
  if (amLast) {
    __threadfence();                        // acquire: see other XCDs' partials
    if (tid < 64) {
      int row = bx * 64 + tid;
      float v[NCLS];
#pragma unroll
      for (int c = 0; c < NCLS; c += 2) {
        float2 bb = *(const float2*)(bias + c);
        v[c] = bb.x; v[c + 1] = bb.y;
      }
      for (int y = 0; y < 7; ++y) {
        const float* pp = partial + ((size_t)y * B_ROWS + row) * NCLS;
#pragma unroll
        for (int c = 0; c < NCLS; c += 2) {
          float2 t = *(const float2*)(pp + c);
          v[c] += t.x; v[c + 1] += t.y;
        }
      }
      float m = v[0];
#pragma unroll
      for (int c = 1; c < NCLS; ++c) m = fmaxf(m, v[c]);
      float sum = 0.0f;
#pragma unroll
      for (int c = 0; c < NCLS; ++c) sum += __expf(v[c] - m);
      float lse = m + __logf(sum);
#pragma unroll
      for (int c = 0; c < NCLS; c += 2) {
        float2 o = {v[c] - lse, v[c + 1] - lse};
        *(float2*)(out + (size_t)row * NCLS + c) = o;
      }
    }
  }
}

extern "C" void kernel_launch(void* const* d_in, const int* in_sizes, int n_in,
                              void* d_out, int out_size, void* d_ws, size_t ws_size,
                              hipStream_t stream) {
  const float* x      = (const float*)d_in[0];
  const float* protos = (const float*)d_in[1];
  const float* W      = (const float*)d_in[2];
  const float* bias   = (const float*)d_in[3];
  float* out = (float*)d_out;
  float* ws  = (float*)d_ws;

  quanv_prep<<<(NPATCH * NPROTO * NCLS + 255) / 256, 256, 0, stream>>>(W, protos, ws);
  quanv_main<<<dim3(B_ROWS / 64, 7), 256, 0, stream>>>(
      x, ws, ws + PART_OFF, (int*)(ws + CNT_OFF), bias, out);
}

// Round 6
// 96.447 us; speedup vs baseline: 1.6326x; 1.6326x over previous
//
#include <hip/hip_runtime.h>
#include <math.h>

#define B_ROWS 8192
#define NPROTO 10
#define NCLS   10
#define NPATCH 196

// workspace layout (floats)
#define TABLE_OFF 0                          // 80: per proto [cy0..3, sy0..3]
#define WT2_OFF   128                        // 19600: [p][proto*10+c]
#define PART_OFF  19776                      // 14*8192*10 partial logits
#define XS_STRIDE 57                         // 57%32=25, gcd(25,32)=1 -> 2-way (free)

typedef float v2f __attribute__((ext_vector_type(2)));

// ---------- prep: sincos table + weight transpose ----------
__global__ __launch_bounds__(256) void quanv_prep(
    const float* __restrict__ W, const float* __restrict__ protos,
    float* __restrict__ ws) {
  int idx = blockIdx.x * 256 + threadIdx.x;
  if (idx < NPROTO * 8) {
    int proto = idx >> 3;
    int j = idx & 7;
    float h = 0.5f * protos[proto * 4 + (j & 3)];
    ws[TABLE_OFF + idx] = (j < 4) ? __cosf(h) : __sinf(h);
  }
  if (idx < NPATCH * NPROTO * NCLS) {
    int p     = idx / (NPROTO * NCLS);
    int rem   = idx - p * (NPROTO * NCLS);
    int proto = rem / NCLS;
    int c     = rem - proto * NCLS;
    ws[WT2_OFF + idx] = W[c * (NPROTO * NPATCH) + proto * NPATCH + p];
  }
}

// ---------- main: 1 patch-row/block (7 blocks/CU), LDS-staged x, scalar weights ----------
__global__ __launch_bounds__(256, 8) void quanv_main(
    const float* __restrict__ x, const float* __restrict__ ws,
    float* __restrict__ partial) {
  __shared__ float xs[64 * XS_STRIDE];      // 14.6 KB; reused as reduction buffer

  const int tid = threadIdx.x;
  const int bx  = blockIdx.x;               // row group (64 rows)
  const int pr  = blockIdx.y;               // patch-row 0..13

  // Stage 64 rows x 56 floats (image rows 2pr,2pr+1), coalesced float4 reads.
  {
    const float* src = x + (size_t)bx * 64 * 784 + pr * 56;
    for (int i = tid; i < 64 * 14; i += 256) {
      int row = i / 14, quad = i - row * 14;
      float4 v = *(const float4*)(src + (size_t)row * 784 + quad * 4);
      float* d = &xs[row * XS_STRIDE + quad * 4];
      d[0] = v.x; d[1] = v.y; d[2] = v.z; d[3] = v.w;
    }
  }
  __syncthreads();

  // readfirstlane -> provably wave-uniform patch index -> scalar weight loads
  const int wid  = __builtin_amdgcn_readfirstlane(tid >> 6);
  const int lane = tid & 63;                // lane = row within group
  const float* tb  = ws + TABLE_OFF;
  const float* Wt2 = ws + WT2_OFF;
  const float* xr  = &xs[lane * XS_STRIDE];

  const int pj0 = (wid < 2) ? wid * 4 : 8 + (wid - 2) * 3;  // 0,4,8,11
  const int npj = (wid < 2) ? 4 : 3;

  v2f acc2[5];
#pragma unroll
  for (int k = 0; k < 5; ++k) acc2[k] = (v2f){0.0f, 0.0f};

  for (int j = 0; j < npj; ++j) {
    int pj  = pj0 + j;                      // patch column 0..13 (uniform)
    int off = 2 * pj;
    float x0 = xr[off],      x1 = xr[off + 1];
    float x2 = xr[off + 28], x3 = xr[off + 29];
    float s0, c0, s1, c1, s2, c2, s3, c3;
    __sincosf(0.5f * x0, &s0, &c0);
    __sincosf(0.5f * x1, &s1, &c1);
    __sincosf(0.5f * x2, &s2, &c2);
    __sincosf(0.5f * x3, &s3, &c3);
    v2f cv01 = {c0, c1}, cv23 = {c2, c3};
    v2f sv01 = {s0, s1}, sv23 = {s2, s3};

    int p = pr * 14 + pj;                   // global patch (uniform)
    const float* wp = Wt2 + p * (NPROTO * NCLS);
#pragma unroll
    for (int proto = 0; proto < NPROTO; ++proto) {
      const float* t8 = tb + proto * 8;     // uniform -> s_load
      v2f tc01 = {t8[0], t8[1]}, tc23 = {t8[2], t8[3]};
      v2f ts01 = {t8[4], t8[5]}, ts23 = {t8[6], t8[7]};
      v2f t01 = __builtin_elementwise_fma(cv01, tc01, sv01 * ts01);
      v2f t23 = __builtin_elementwise_fma(cv23, tc23, sv23 * ts23);
      float q  = fabsf((t01.x * t01.y) * (t23.x * t23.y));
      v2f qq = {q, q};
      const v2f* wv = (const v2f*)(wp + proto * NCLS);  // uniform -> s_load
#pragma unroll
      for (int k = 0; k < 5; ++k)
        acc2[k] = __builtin_elementwise_fma(qq, wv[k], acc2[k]);
    }
  }

  // cross-wave reduction: reuse xs (dead after patch loop), stride 11
  __syncthreads();
  {
    float* myred = &xs[(wid * 64 + lane) * 11];
#pragma unroll
    for (int k = 0; k < 5; ++k) {
      myred[2 * k]     = acc2[k].x;
      myred[2 * k + 1] = acc2[k].y;
    }
  }
  __syncthreads();

  for (int i = tid; i < 64 * NCLS; i += 256) {
    int row = i / NCLS, c = i - row * NCLS;
    int o = row * 11 + c;
    float s = xs[o] + xs[704 + o] + xs[1408 + o] + xs[2112 + o];
    partial[((size_t)pr * B_ROWS + (size_t)bx * 64 + row) * NCLS + c] = s;
  }
}

// ---------- final: sum 14 partials + bias + log_softmax ----------
__global__ __launch_bounds__(256) void quanv_final(
    const float* __restrict__ partial, const float* __restrict__ bias,
    float* __restrict__ out) {
  int r = blockIdx.x * 256 + threadIdx.x;
  float v[NCLS];
#pragma unroll
  for (int c = 0; c < NCLS; c += 2) {
    float2 bb = *(const float2*)(bias + c);
    v[c] = bb.x; v[c + 1] = bb.y;
  }
  for (int y = 0; y < 14; ++y) {
    const float* pp = partial + ((size_t)y * B_ROWS + r) * NCLS;
#pragma unroll
    for (int c = 0; c < NCLS; c += 2) {
      float2 t = *(const float2*)(pp + c);
      v[c] += t.x; v[c + 1] += t.y;
    }
  }
  float m = v[0];
#pragma unroll
  for (int c = 1; c < NCLS; ++c) m = fmaxf(m, v[c]);
  float sum = 0.0f;
#pragma unroll
  for (int c = 0; c < NCLS; ++c) sum += __expf(v[c] - m);
  float lse = m + __logf(sum);
#pragma unroll
  for (int c = 0; c < NCLS; c += 2) {
    float2 o = {v[c] - lse, v[c + 1] - lse};
    *(float2*)(out + (size_t)r * NCLS + c) = o;
  }
}

extern "C" void kernel_launch(void* const* d_in, const int* in_sizes, int n_in,
                              void* d_out, int out_size, void* d_ws, size_t ws_size,
                              hipStream_t stream) {
  const float* x      = (const float*)d_in[0];
  const float* protos = (const float*)d_in[1];
  const float* W      = (const float*)d_in[2];
  const float* bias   = (const float*)d_in[3];
  float* out = (float*)d_out;
  float* ws  = (float*)d_ws;

  quanv_prep<<<(NPATCH * NPROTO * NCLS + 255) / 256, 256, 0, stream>>>(W, protos, ws);
  quanv_main<<<dim3(B_ROWS / 64, 14), 256, 0, stream>>>(x, ws, ws + PART_OFF);
  quanv_final<<<B_ROWS / 256, 256, 0, stream>>>(ws + PART_OFF, bias, out);
}

// Round 7
// 91.808 us; speedup vs baseline: 1.7151x; 1.0505x over previous
//
#include <hip/hip_runtime.h>
#include <math.h>

#define B_ROWS 8192
#define NPROTO 10
#define NCLS   10
#define NPATCH 196
#define WROW   (NPROTO * NPATCH)            // 1960: W row length

// workspace layout (floats): only partials now
#define PART_OFF  0                          // 7*8192*10 partial logits
#define XS_STRIDE 113                        // 113%32=17, gcd(17,32)=1 -> conflict-free

typedef float v2f __attribute__((ext_vector_type(2)));

// ---------- main: LDS-staged x, inline table, direct scalar W reads ----------
__global__ __launch_bounds__(256) void quanv_main(
    const float* __restrict__ x, const float* __restrict__ protos,
    const float* __restrict__ W, float* __restrict__ partial) {
  __shared__ float xs[64 * XS_STRIDE];      // 28.9 KB; reused as reduction buffer
  __shared__ float tbl[80];                 // per proto [cy0..3, sy0..3]

  const int tid = threadIdx.x;
  const int bx  = blockIdx.x;               // row group (64 rows)
  const int pr2 = blockIdx.y;               // pair of patch-rows, 0..6

  // Inline table build: 80 threads, one sincos each (replaces the prep kernel)
  if (tid < 80) {
    int proto = tid >> 3, j = tid & 7;
    float h = 0.5f * protos[proto * 4 + (j & 3)];
    tbl[tid] = (j < 4) ? __cosf(h) : __sinf(h);
  }

  // Stage 64 rows x 112 floats (image rows 4*pr2..4*pr2+3), coalesced float4.
  {
    const float* src = x + (size_t)bx * 64 * 784 + pr2 * 112;
    for (int i = tid; i < 64 * 28; i += 256) {
      int row = i / 28, quad = i - row * 28;
      float4 v = *(const float4*)(src + (size_t)row * 784 + quad * 4);
      float* d = &xs[row * XS_STRIDE + quad * 4];
      d[0] = v.x; d[1] = v.y; d[2] = v.z; d[3] = v.w;
    }
  }
  __syncthreads();

  // readfirstlane -> provably wave-uniform patch index -> scalar W loads
  const int wid  = __builtin_amdgcn_readfirstlane(tid >> 6);
  const int lane = tid & 63;                // lane = row within group
  const float* xr = &xs[lane * XS_STRIDE];
  const int p0 = pr2 * 28 + wid * 7;        // this wave's first global patch (uniform)

  // Precompute angle sincos for this wave's 7 patches (56 VGPRs)
  v2f cv01[7], cv23[7], sv01[7], sv23[7];
#pragma unroll
  for (int j = 0; j < 7; ++j) {
    int lp  = wid * 7 + j;                  // local patch 0..27 (uniform)
    int piL = lp >= 14 ? 1 : 0;
    int pj  = lp - piL * 14;
    int off = piL * 56 + 2 * pj;
    float x0 = xr[off],      x1 = xr[off + 1];
    float x2 = xr[off + 28], x3 = xr[off + 29];
    float s0, c0, s1, c1, s2, c2, s3, c3;
    __sincosf(0.5f * x0, &s0, &c0);
    __sincosf(0.5f * x1, &s1, &c1);
    __sincosf(0.5f * x2, &s2, &c2);
    __sincosf(0.5f * x3, &s3, &c3);
    cv01[j] = (v2f){c0, c1}; cv23[j] = (v2f){c2, c3};
    sv01[j] = (v2f){s0, s1}; sv23[j] = (v2f){s2, s3};
  }

  v2f acc2[5];
#pragma unroll
  for (int k = 0; k < 5; ++k) acc2[k] = (v2f){0.0f, 0.0f};

#pragma unroll
  for (int proto = 0; proto < NPROTO; ++proto) {
    // 8 table floats via two b128 broadcast LDS reads
    float4 tc = *(const float4*)&tbl[proto * 8];
    float4 ts = *(const float4*)&tbl[proto * 8 + 4];
    v2f tc01 = {tc.x, tc.y}, tc23 = {tc.z, tc.w};
    v2f ts01 = {ts.x, ts.y}, ts23 = {ts.z, ts.w};
    const float* wbase = W + proto * NPATCH + p0;   // uniform
#pragma unroll
    for (int j = 0; j < 7; ++j) {
      v2f t01 = __builtin_elementwise_fma(cv01[j], tc01, sv01[j] * ts01);
      v2f t23 = __builtin_elementwise_fma(cv23[j], tc23, sv23[j] * ts23);
      float q = fabsf((t01.x * t01.y) * (t23.x * t23.y));
      v2f qq = {q, q};
      const float* wq = wbase + j;          // uniform -> s_load_dword x10
#pragma unroll
      for (int k = 0; k < 5; ++k) {
        v2f wv = {wq[(2 * k) * WROW], wq[(2 * k + 1) * WROW]};
        acc2[k] = __builtin_elementwise_fma(qq, wv, acc2[k]);
      }
    }
  }

  // cross-wave reduction: reuse xs (dead after patch loop), stride 11
  __syncthreads();
  {
    float* myred = &xs[(wid * 64 + lane) * 11];
#pragma unroll
    for (int k = 0; k < 5; ++k) {
      myred[2 * k]     = acc2[k].x;
      myred[2 * k + 1] = acc2[k].y;
    }
  }
  __syncthreads();

  for (int i = tid; i < 64 * NCLS; i += 256) {
    int row = i / NCLS, c = i - row * NCLS;
    int o = row * 11 + c;
    float s = xs[o] + xs[704 + o] + xs[1408 + o] + xs[2112 + o];
    partial[((size_t)pr2 * B_ROWS + (size_t)bx * 64 + row) * NCLS + c] = s;
  }
}

// ---------- final: sum 7 partials + bias + log_softmax ----------
__global__ __launch_bounds__(256) void quanv_final(
    const float* __restrict__ partial, const float* __restrict__ bias,
    float* __restrict__ out) {
  int r = blockIdx.x * 256 + threadIdx.x;
  float v[NCLS];
#pragma unroll
  for (int c = 0; c < NCLS; c += 2) {
    float2 bb = *(const float2*)(bias + c);
    v[c] = bb.x; v[c + 1] = bb.y;
  }
  for (int y = 0; y < 7; ++y) {
    const float* pp = partial + ((size_t)y * B_ROWS + r) * NCLS;
#pragma unroll
    for (int c = 0; c < NCLS; c += 2) {
      float2 t = *(const float2*)(pp + c);
      v[c] += t.x; v[c + 1] += t.y;
    }
  }
  float m = v[0];
#pragma unroll
  for (int c = 1; c < NCLS; ++c) m = fmaxf(m, v[c]);
  float sum = 0.0f;
#pragma unroll
  for (int c = 0; c < NCLS; ++c) sum += __expf(v[c] - m);
  float lse = m + __logf(sum);
#pragma unroll
  for (int c = 0; c < NCLS; c += 2) {
    float2 o = {v[c] - lse, v[c + 1] - lse};
    *(float2*)(out + (size_t)r * NCLS + c) = o;
  }
}

extern "C" void kernel_launch(void* const* d_in, const int* in_sizes, int n_in,
                              void* d_out, int out_size, void* d_ws, size_t ws_size,
                              hipStream_t stream) {
  const float* x      = (const float*)d_in[0];
  const float* protos = (const float*)d_in[1];
  const float* W      = (const float*)d_in[2];
  const float* bias   = (const float*)d_in[3];
  float* out = (float*)d_out;
  float* ws  = (float*)d_ws;

  quanv_main<<<dim3(B_ROWS / 64, 7), 256, 0, stream>>>(x, protos, W, ws + PART_OFF);
  quanv_final<<<B_ROWS / 256, 256, 0, stream>>>(ws + PART_OFF, bias, out);
}